// Round 4
// baseline (81.395 us; speedup 1.0000x reference)
//
#include <hip/hip_runtime.h>

#define B_ 4
#define C_ 64
#define N_ 512
#define H_ 128   // hidden width = 2C

// ---------------------------------------------------------------------------
// Kernel 1: factorized first-layer projections.
//   L[b,i,h] = sum_c x[b,c,i] * W1[c,h]
//   R[b,j,h] = sum_c x[b,c,j] * W1[64+c,h] + b1[h]   (b1 folded into R)
// Output layout: [b][row][h], h contiguous (stride H_).
// Grid: 256 blocks = 2 halves x 4 b x 32 i-tiles(16 rows). Block 256 threads.
// ---------------------------------------------------------------------------
__global__ __launch_bounds__(256) void proj_kernel(
    const float* __restrict__ x, const float* __restrict__ W1,
    const float* __restrict__ b1, float* __restrict__ Lbuf,
    float* __restrict__ Rbuf)
{
    __shared__ float Wl[64 * 128];   // 32 KB: one half of W1 (64 rows x 128 cols)
    __shared__ float xs[16 * 68];    // x tile, transposed [ii][c], padded stride 68

    const int t    = threadIdx.x;
    const int half = blockIdx.x >> 7;          // 0 = L, 1 = R
    const int rem  = blockIdx.x & 127;
    const int b    = rem >> 5;
    const int i0   = (rem & 31) * 16;
    const int cbase = half * 64;

    // stage W half: rows cbase..cbase+63, all 128 cols = 2048 float4, coalesced
    const float4* W14 = (const float4*)W1;
    float4* Wl4 = (float4*)Wl;
    #pragma unroll
    for (int k = 0; k < 8; ++k)
        Wl4[t + k * 256] = W14[cbase * 32 + t + k * 256];

    // stage x tile: xs[ii*68 + c] = x[b, c, i0+ii]
    #pragma unroll
    for (int k = 0; k < 4; ++k) {
        int idx = t + k * 256;                  // 0..1023
        int c = idx >> 4, ii = idx & 15;
        xs[ii * 68 + c] = x[b * (C_ * N_) + c * N_ + i0 + ii];
    }
    __syncthreads();

    const int hq  = t & 31;           // column quad (4 h's)
    const int il  = (t >> 5) * 2;     // local row base (2 rows per thread)
    const int col = hq * 4;

    float4 a0, a1;
    if (half) { a0 = *(const float4*)(b1 + col); a1 = a0; }
    else      { a0 = make_float4(0.f, 0.f, 0.f, 0.f); a1 = a0; }

    #pragma unroll
    for (int c = 0; c < 64; c += 4) {
        float4 xv0 = *(float4*)(xs + il * 68 + c);
        float4 xv1 = *(float4*)(xs + (il + 1) * 68 + c);
        const float* x0p = (const float*)&xv0;
        const float* x1p = (const float*)&xv1;
        #pragma unroll
        for (int cc = 0; cc < 4; ++cc) {
            float4 w = Wl4[(c + cc) * 32 + hq];
            a0.x = fmaf(w.x, x0p[cc], a0.x);
            a0.y = fmaf(w.y, x0p[cc], a0.y);
            a0.z = fmaf(w.z, x0p[cc], a0.z);
            a0.w = fmaf(w.w, x0p[cc], a0.w);
            a1.x = fmaf(w.x, x1p[cc], a1.x);
            a1.y = fmaf(w.y, x1p[cc], a1.y);
            a1.z = fmaf(w.z, x1p[cc], a1.z);
            a1.w = fmaf(w.w, x1p[cc], a1.w);
        }
    }

    float* buf = half ? Rbuf : Lbuf;
    float* o = buf + b * (N_ * H_) + (i0 + il) * H_ + col;
    *(float4*)o = a0;
    *(float4*)(o + H_) = a1;
}

// ---------------------------------------------------------------------------
// Kernel 2: pairwise scores, LDS/VALU-balanced version.
//   out[b,i,j] = (j > i) ? sum_h relu(L[i,h] + R[j,h]) * W2[h] + b2 : 0
// Grid: 4 b x 256 tiles (16x16 of 32x32) = 1024 blocks, 64 threads (1 wave).
// Thread tile 4x4 -> 0.5 ds_read_b128 per output per h-quad: LDS pipe
// (~6.5K cyc/CU) balances the VALU floor (~6.5K cyc/SIMD).
// XOR swizzle sc = hc ^ (row>>2): compute-phase reads hit 8 quad-addresses
// distinct mod 8 -> all 32 banks exactly once (conflict-free, 8-lane
// broadcast); staging writes are 2-way (free per m136).
// LDS 32 KB -> 5 blocks/CU; 544 fine-grained work blocks balance dynamically.
// ---------------------------------------------------------------------------
__global__ __launch_bounds__(64) void pair_kernel(
    const float* __restrict__ Lbuf, const float* __restrict__ Rbuf,
    const float* __restrict__ W2, const float* __restrict__ b2,
    float* __restrict__ out)
{
    __shared__ float4 Lt4[32 * 32];   // 16 KB
    __shared__ float4 Rt4[32 * 32];   // 16 KB

    const int t    = threadIdx.x;     // 0..63
    const int b    = blockIdx.x >> 8;
    const int tile = blockIdx.x & 255;
    const int ti0  = (tile >> 4) * 32;
    const int tj0  = (tile & 15) * 32;

    float* outb = out + b * (N_ * N_);

    if (tj0 + 31 <= ti0) {
        // tile entirely in strict lower triangle (j <= i everywhere): zeros.
        // 32 rows x 8 float4-cols = 256 float4 -> 4 iters x 64 threads.
        float4 z = make_float4(0.f, 0.f, 0.f, 0.f);
        #pragma unroll
        for (int k = 0; k < 4; ++k) {
            int idx = t + k * 64;              // 0..255
            int r = idx >> 3, cq = idx & 7;    // r: 0..31, cq: 0..7
            *(float4*)(outb + (ti0 + r) * N_ + tj0 + cq * 4) = z;
        }
        return;
    }

    // stage L and R tiles: 1024 float4 each. Source rows are contiguous
    // (H_=128 floats), so idx*4 floats == row*H_ + hc*4 -> fully coalesced.
    const float* Lsrc = Lbuf + b * (N_ * H_) + ti0 * H_;
    const float* Rsrc = Rbuf + b * (N_ * H_) + tj0 * H_;
    #pragma unroll
    for (int k = 0; k < 16; ++k) {
        int idx = t + k * 64;                  // 0..1023
        int row = idx >> 5, hc = idx & 31;
        int sc = hc ^ (row >> 2);              // XOR swizzle
        Lt4[row * 32 + sc] = *(const float4*)(Lsrc + idx * 4);
        Rt4[row * 32 + sc] = *(const float4*)(Rsrc + idx * 4);
    }
    __syncthreads();

    const int gL  = t >> 3;            // 0..7  -> row group
    const int gR  = t & 7;             // 0..7  -> col group
    const int til = gL * 4, tjl = gR * 4;

    float acc[4][4];
    #pragma unroll
    for (int r = 0; r < 4; ++r)
        #pragma unroll
        for (int c = 0; c < 4; ++c) acc[r][c] = 0.f;

    const float4* W24 = (const float4*)W2;

    #pragma unroll 2
    for (int hc = 0; hc < 32; ++hc) {
        const int scL = hc ^ gL;
        const int scR = hc ^ gR;
        float4 Lr[4], Rc[4];
        #pragma unroll
        for (int r = 0; r < 4; ++r) Lr[r] = Lt4[(til + r) * 32 + scL];
        #pragma unroll
        for (int c = 0; c < 4; ++c) Rc[c] = Rt4[(tjl + c) * 32 + scR];
        float4 wv = W24[hc];               // wave-uniform -> s_load
        const float* wp = (const float*)&wv;
        #pragma unroll
        for (int r = 0; r < 4; ++r) {
            const float* lp = (const float*)&Lr[r];
            #pragma unroll
            for (int c = 0; c < 4; ++c) {
                const float* rp = (const float*)&Rc[c];
                float s = acc[r][c];
                #pragma unroll
                for (int k = 0; k < 4; ++k) {
                    float v = fmaxf(lp[k] + rp[k], 0.f);
                    s = fmaf(v, wp[k], s);
                }
                acc[r][c] = s;
            }
        }
    }

    const float bias2 = b2[0];
    #pragma unroll
    for (int r = 0; r < 4; ++r) {
        const int gi = ti0 + til + r;
        float4 v;
        float* vp = (float*)&v;
        #pragma unroll
        for (int c = 0; c < 4; ++c) {
            const int gj = tj0 + tjl + c;
            vp[c] = (gj > gi) ? (acc[r][c] + bias2) : 0.f;
        }
        *(float4*)(outb + gi * N_ + tj0 + tjl) = v;
    }
}

extern "C" void kernel_launch(void* const* d_in, const int* in_sizes, int n_in,
                              void* d_out, int out_size, void* d_ws, size_t ws_size,
                              hipStream_t stream)
{
    const float* x  = (const float*)d_in[0];
    const float* W1 = (const float*)d_in[1];
    const float* b1 = (const float*)d_in[2];
    const float* W2 = (const float*)d_in[3];
    const float* b2 = (const float*)d_in[4];
    float* out  = (float*)d_out;
    float* Lbuf = (float*)d_ws;                 // B*N*H floats = 1 MB
    float* Rbuf = Lbuf + B_ * N_ * H_;          // +1 MB

    proj_kernel<<<256, 256, 0, stream>>>(x, W1, b1, Lbuf, Rbuf);
    pair_kernel<<<B_ * 256, 64, 0, stream>>>(Lbuf, Rbuf, W2, b2, out);
}

// Round 5
// 78.397 us; speedup vs baseline: 1.0382x; 1.0382x over previous
//
#include <hip/hip_runtime.h>

#define B_ 4
#define C_ 64
#define N_ 512
#define H_ 128   // hidden width = 2C

// ---------------------------------------------------------------------------
// Kernel 1: factorized first-layer projections.
//   L[b,i,h] = sum_c x[b,c,i] * W1[c,h]
//   R[b,j,h] = sum_c x[b,c,j] * W1[64+c,h] + b1[h]   (b1 folded into R)
// ---------------------------------------------------------------------------
__global__ __launch_bounds__(256) void proj_kernel(
    const float* __restrict__ x, const float* __restrict__ W1,
    const float* __restrict__ b1, float* __restrict__ Lbuf,
    float* __restrict__ Rbuf)
{
    __shared__ float Wl[64 * 128];   // 32 KB: one half of W1
    __shared__ float xs[16 * 68];    // x tile, transposed [ii][c], stride 68

    const int t    = threadIdx.x;
    const int half = blockIdx.x >> 7;          // 0 = L, 1 = R
    const int rem  = blockIdx.x & 127;
    const int b    = rem >> 5;
    const int i0   = (rem & 31) * 16;
    const int cbase = half * 64;

    const float4* W14 = (const float4*)W1;
    float4* Wl4 = (float4*)Wl;
    #pragma unroll
    for (int k = 0; k < 8; ++k)
        Wl4[t + k * 256] = W14[cbase * 32 + t + k * 256];

    #pragma unroll
    for (int k = 0; k < 4; ++k) {
        int idx = t + k * 256;                  // 0..1023
        int c = idx >> 4, ii = idx & 15;
        xs[ii * 68 + c] = x[b * (C_ * N_) + c * N_ + i0 + ii];
    }
    __syncthreads();

    const int hq  = t & 31;
    const int il  = (t >> 5) * 2;
    const int col = hq * 4;

    float4 a0, a1;
    if (half) { a0 = *(const float4*)(b1 + col); a1 = a0; }
    else      { a0 = make_float4(0.f, 0.f, 0.f, 0.f); a1 = a0; }

    #pragma unroll
    for (int c = 0; c < 64; c += 4) {
        float4 xv0 = *(float4*)(xs + il * 68 + c);
        float4 xv1 = *(float4*)(xs + (il + 1) * 68 + c);
        const float* x0p = (const float*)&xv0;
        const float* x1p = (const float*)&xv1;
        #pragma unroll
        for (int cc = 0; cc < 4; ++cc) {
            float4 w = Wl4[(c + cc) * 32 + hq];
            a0.x = fmaf(w.x, x0p[cc], a0.x);
            a0.y = fmaf(w.y, x0p[cc], a0.y);
            a0.z = fmaf(w.z, x0p[cc], a0.z);
            a0.w = fmaf(w.w, x0p[cc], a0.w);
            a1.x = fmaf(w.x, x1p[cc], a1.x);
            a1.y = fmaf(w.y, x1p[cc], a1.y);
            a1.z = fmaf(w.z, x1p[cc], a1.z);
            a1.w = fmaf(w.w, x1p[cc], a1.w);
        }
    }

    float* buf = half ? Rbuf : Lbuf;
    float* o = buf + b * (N_ * H_) + (i0 + il) * H_ + col;
    *(float4*)o = a0;
    *(float4*)(o + H_) = a1;
}

// ---------------------------------------------------------------------------
// Kernel 2: pairwise scores — split-h across waves.
//   out[b,i,j] = (j > i) ? sum_h relu(L[i,h] + R[j,h]) * W2[h] + b2 : 0
// Grid: 4 b x 256 tiles of 32x32 = 1024 blocks, 256 threads (4 waves).
// Each wave computes the FULL 32x32 tile (4x4 per thread) over its own
// 32-h slice (8 hc iters) -> 4x4 LDS traffic (0.5 b128/output/h-quad)
// AND 2176 work waves (2.1/SIMD) for latency hiding. Partials are summed
// via a 16 KB LDS reduction buffer reused over Lt.
// XOR swizzle sc = hc ^ (row>>2): compute reads hit 8 distinct quad-
// addresses, one per 4-bank group, 8-lane broadcast -> conflict-free.
// LDS 32 KB -> 5 blocks/CU.
// ---------------------------------------------------------------------------
__global__ __launch_bounds__(256) void pair_kernel(
    const float* __restrict__ Lbuf, const float* __restrict__ Rbuf,
    const float* __restrict__ W2, const float* __restrict__ b2,
    float* __restrict__ out)
{
    __shared__ float4 Lt4[32 * 32];   // 16 KB (reused as reduction buffer)
    __shared__ float4 Rt4[32 * 32];   // 16 KB

    const int t    = threadIdx.x;     // 0..255
    const int b    = blockIdx.x >> 8;
    const int tile = blockIdx.x & 255;
    const int ti0  = (tile >> 4) * 32;
    const int tj0  = (tile & 15) * 32;

    float* outb = out + b * (N_ * N_);

    if (tj0 + 31 <= ti0) {
        // tile entirely in strict lower triangle: zeros. 256 float4 total.
        int r = t >> 3, cq = t & 7;
        *(float4*)(outb + (ti0 + r) * N_ + tj0 + cq * 4) =
            make_float4(0.f, 0.f, 0.f, 0.f);
        return;
    }

    // stage L and R tiles: 1024 float4 each, coalesced (rows contiguous).
    const float* Lsrc = Lbuf + b * (N_ * H_) + ti0 * H_;
    const float* Rsrc = Rbuf + b * (N_ * H_) + tj0 * H_;
    #pragma unroll
    for (int k = 0; k < 4; ++k) {
        int idx = t + k * 256;                 // 0..1023
        int row = idx >> 5, hc = idx & 31;
        int sc = hc ^ (row >> 2);              // XOR swizzle
        Lt4[row * 32 + sc] = *(const float4*)(Lsrc + idx * 4);
        Rt4[row * 32 + sc] = *(const float4*)(Rsrc + idx * 4);
    }
    __syncthreads();

    const int wave = t >> 6;
    const int lane = t & 63;
    const int gL   = lane >> 3;        // 0..7
    const int gR   = lane & 7;         // 0..7
    const int til  = gL * 4, tjl = gR * 4;
    const int hc0  = wave * 8;         // this wave's h-slice (32 h)

    float acc[4][4];
    #pragma unroll
    for (int r = 0; r < 4; ++r)
        #pragma unroll
        for (int c = 0; c < 4; ++c) acc[r][c] = 0.f;

    const float4* W24 = (const float4*)W2;

    #pragma unroll
    for (int k8 = 0; k8 < 8; ++k8) {
        const int hc  = hc0 + k8;
        const int scL = hc ^ gL;
        const int scR = hc ^ gR;
        float4 Lr[4], Rc[4];
        #pragma unroll
        for (int r = 0; r < 4; ++r) Lr[r] = Lt4[(til + r) * 32 + scL];
        #pragma unroll
        for (int c = 0; c < 4; ++c) Rc[c] = Rt4[(tjl + c) * 32 + scR];
        float4 wv = W24[hc];               // wave-uniform -> s_load
        const float* wp = (const float*)&wv;
        #pragma unroll
        for (int r = 0; r < 4; ++r) {
            const float* lp = (const float*)&Lr[r];
            #pragma unroll
            for (int c = 0; c < 4; ++c) {
                const float* rp = (const float*)&Rc[c];
                float s = acc[r][c];
                #pragma unroll
                for (int k = 0; k < 4; ++k) {
                    float v = fmaxf(lp[k] + rp[k], 0.f);
                    s = fmaf(v, wp[k], s);
                }
                acc[r][c] = s;
            }
        }
    }

    // cross-wave reduction: redq[wave][row][colquad], 4 x 4 KB over Lt4.
    __syncthreads();                       // all Lt/Rt reads done
    float4* redq = Lt4;
    #pragma unroll
    for (int r = 0; r < 4; ++r)
        redq[wave * 256 + (til + r) * 8 + gR] =
            make_float4(acc[r][0], acc[r][1], acc[r][2], acc[r][3]);
    __syncthreads();

    // final: thread t -> row r = t>>3 (0..31), col quad cq = t&7.
    {
        const int r  = t >> 3;
        const int cq = t & 7;
        float4 s0 = redq[r * 8 + cq];
        float4 s1 = redq[256 + r * 8 + cq];
        float4 s2 = redq[512 + r * 8 + cq];
        float4 s3 = redq[768 + r * 8 + cq];
        const float bias2 = b2[0];
        const int gi = ti0 + r;
        const int gj0 = tj0 + cq * 4;
        float4 v;
        v.x = (gj0     > gi) ? (s0.x + s1.x + s2.x + s3.x + bias2) : 0.f;
        v.y = (gj0 + 1 > gi) ? (s0.y + s1.y + s2.y + s3.y + bias2) : 0.f;
        v.z = (gj0 + 2 > gi) ? (s0.z + s1.z + s2.z + s3.z + bias2) : 0.f;
        v.w = (gj0 + 3 > gi) ? (s0.w + s1.w + s2.w + s3.w + bias2) : 0.f;
        *(float4*)(outb + gi * N_ + gj0) = v;
    }
}

extern "C" void kernel_launch(void* const* d_in, const int* in_sizes, int n_in,
                              void* d_out, int out_size, void* d_ws, size_t ws_size,
                              hipStream_t stream)
{
    const float* x  = (const float*)d_in[0];
    const float* W1 = (const float*)d_in[1];
    const float* b1 = (const float*)d_in[2];
    const float* W2 = (const float*)d_in[3];
    const float* b2 = (const float*)d_in[4];
    float* out  = (float*)d_out;
    float* Lbuf = (float*)d_ws;                 // B*N*H floats = 1 MB
    float* Rbuf = Lbuf + B_ * N_ * H_;          // +1 MB

    proj_kernel<<<256, 256, 0, stream>>>(x, W1, b1, Lbuf, Rbuf);
    pair_kernel<<<B_ * 256, 256, 0, stream>>>(Lbuf, Rbuf, W2, b2, out);
}